// Round 5
// baseline (353.748 us; speedup 1.0000x reference)
//
#include <hip/hip_runtime.h>
#include <math.h>

#define CNUM 19
#define NB 4
#define HW 589824            // 768*768
#define NPIX 2359296         // NB*HW

// k_fused: 256 threads x 4 px = 1024 px/block -> grid (576, 4)
#define TPB 256
#define PXT 4
#define TILE (TPB * PXT)     // 1024; HW % TILE == 0

typedef float f32x4 __attribute__((ext_vector_type(4)));

// ---------------------------------------------------------------- workspace
// Per-class partial sums; weights are applied in k_final, which removes the
// histogram->main dependency entirely (k_hist eliminated: N_c IS the hist).
struct ImgAcc2 {
  double sS[CNUM];          // sum of -log p  over valid px of class c
  double sA[CNUM];          // same, att-masked (edge > 0.8)
  unsigned int cS[CNUM];    // count (== histogram bin)
  unsigned int cA[CNUM];    // att count (== att histogram bin)
  unsigned int pad[2];
};

struct Ws {
  ImgAcc2 img[NB];
  double bce_p, bce_n;      // sum of bce over pos / neg px (batch-global)
  unsigned int np, nn;      // pos / neg counts (batch-global)
};

// ---------------------------------------------------------------- init
__global__ void k_init(Ws* ws) {
  unsigned int* p = (unsigned int*)ws;
  const int nw = (int)(sizeof(Ws) / 4);
  for (int i = threadIdx.x; i < nw; i += blockDim.x) p[i] = 0u;
}

// ---------------------------------------------------------------- fused main
__global__ __launch_bounds__(TPB, 4) void k_fused(const float* __restrict__ segin,
                                                  const float* __restrict__ edgein,
                                                  const int* __restrict__ segmask,
                                                  const int* __restrict__ edgemask,
                                                  Ws* __restrict__ wsw) {
  const int n = blockIdx.y;
  const int t = threadIdx.x;
  const int tile0 = blockIdx.x * TILE;

  __shared__ float lsS[CNUM], lsA[CNUM];
  __shared__ unsigned int lcS[CNUM], lcA[CNUM];
  __shared__ float sbp, sbn;
  __shared__ unsigned int snp, snn;

  if (t < CNUM) { lsS[t] = 0.f; lsA[t] = 0.f; lcS[t] = 0u; lcA[t] = 0u; }
  if (t == CNUM)     { sbp = 0.f; sbn = 0.f; }
  if (t == CNUM + 1) { snp = 0u;  snn = 0u; }
  __syncthreads();

  const int pxoff = n * HW + tile0 + t * 4;

  // Only segmask needed across the channel loop (small live set, no spill).
  int4 tm = *reinterpret_cast<const int4*>(segmask + pxoff);
  int tcv[PXT];
  unsigned int inbits = 0u;    // bit j: 0 <= target < CNUM (valid AND in-bin)
  {
    int ta[4] = {tm.x, tm.y, tm.z, tm.w};
    #pragma unroll
    for (int j = 0; j < 4; ++j) {
      tcv[j] = min(max(ta[j], 0), CNUM - 1);
      inbits |= (((unsigned)ta[j]) < (unsigned)CNUM) ? (1u << j) : 0u;
    }
  }

  float sacc[PXT] = {0.f, 0.f, 0.f, 0.f};
  float xt[PXT]   = {0.f, 0.f, 0.f, 0.f};

  // Non-temporal: segin is read exactly once; test LLC-path wall vs HBM stream.
  const float* cb = segin + (size_t)n * CNUM * HW + tile0 + t * 4;
  #pragma unroll
  for (int c = 0; c < CNUM; ++c) {
    f32x4 v = __builtin_nontemporal_load(
        reinterpret_cast<const f32x4*>(cb + (size_t)c * HW));
    float va[4] = {v.x, v.y, v.z, v.w};
    #pragma unroll
    for (int j = 0; j < 4; ++j) {
      sacc[j] += __expf(va[j]);
      xt[j] = (tcv[j] == c) ? va[j] : xt[j];
    }
  }

  // Epilogue: edge data now (small), per-class LDS accumulation.
  f32x4 ev = __builtin_nontemporal_load(reinterpret_cast<const f32x4*>(edgein + pxoff));
  int4   em = *reinterpret_cast<const int4*>(edgemask + pxoff);

  float bpos = 0.f, bneg = 0.f;
  int cntp = 0, cntn = 0;
  {
    float ea[4] = {ev.x, ev.y, ev.z, ev.w};
    int   ma[4] = {em.x, em.y, em.z, em.w};
    #pragma unroll
    for (int j = 0; j < PXT; ++j) {
      float nlp = __logf(sacc[j]) - xt[j];     // -log p
      if ((inbits >> j) & 1u) {
        atomicAdd(&lsS[tcv[j]], nlp);
        atomicAdd(&lcS[tcv[j]], 1u);
        if (ea[j] > 0.8f) {
          atomicAdd(&lsA[tcv[j]], nlp);
          atomicAdd(&lcA[tcv[j]], 1u);
        }
      }
      float e = ea[j];
      int m = ma[j];
      float bce = fmaxf(e, 0.f) - e * (float)m + log1pf(__expf(-fabsf(e)));
      if (m == 1) { bpos += bce; ++cntp; }
      else if (m == 0) { bneg += bce; ++cntn; }
    }
  }

  // wave-reduce the bce partials, then per-wave shared atomics
  #pragma unroll
  for (int off = 32; off > 0; off >>= 1) {
    bpos += __shfl_down(bpos, off);
    bneg += __shfl_down(bneg, off);
    cntp += __shfl_down(cntp, off);
    cntn += __shfl_down(cntn, off);
  }
  if ((t & 63) == 0) {
    atomicAdd(&sbp, bpos);
    atomicAdd(&sbn, bneg);
    atomicAdd(&snp, (unsigned int)cntp);
    atomicAdd(&snn, (unsigned int)cntn);
  }
  __syncthreads();

  // flush: parallel global atomics, one accumulator per thread
  if (t < CNUM) {
    atomicAdd(&wsw->img[n].sS[t], (double)lsS[t]);
  } else if (t >= 32 && t < 32 + CNUM) {
    atomicAdd(&wsw->img[n].sA[t - 32], (double)lsA[t - 32]);
  } else if (t >= 64 && t < 64 + CNUM) {
    unsigned int v = lcS[t - 64];
    if (v) atomicAdd(&wsw->img[n].cS[t - 64], v);
  } else if (t >= 96 && t < 96 + CNUM) {
    unsigned int v = lcA[t - 96];
    if (v) atomicAdd(&wsw->img[n].cA[t - 96], v);
  } else if (t == 128) {
    atomicAdd(&wsw->bce_p, (double)sbp);
  } else if (t == 129) {
    atomicAdd(&wsw->bce_n, (double)sbn);
  } else if (t == 130) {
    atomicAdd(&wsw->np, snp);
  } else if (t == 131) {
    atomicAdd(&wsw->nn, snn);
  }
}

// ---------------------------------------------------------------- finalize
// Weights from counts (counts == histogram bins), weighted combine in f64.
__global__ void k_final(const Ws* __restrict__ ws, float* __restrict__ out) {
  if (threadIdx.x == 0 && blockIdx.x == 0) {
    double segl = 0.0, attl = 0.0;
    for (int i = 0; i < NB; ++i) {
      const ImgAcc2* a = &ws->img[i];
      double totS = 0.0, totA = 0.0;
      for (int c = 0; c < CNUM; ++c) { totS += (double)a->cS[c]; totA += (double)a->cA[c]; }
      double numS = 0.0, denS = 0.0, numA = 0.0, denA = 0.0;
      for (int c = 0; c < CNUM; ++c) {
        double bS = (double)a->cS[c];
        double wS = (bS != 0.0 ? (1.0 - bS / totS) : 0.0) + 1.0;
        numS += wS * a->sS[c];
        denS += wS * bS;
        double bA = (double)a->cA[c];
        double wA = (bA != 0.0 ? (1.0 - bA / totA) : 0.0) + 1.0;
        numA += wA * a->sA[c];
        denA += wA * bA;
      }
      segl += numS / denS;
      attl += numA / denA;
    }
    double s = (double)ws->np + (double)ws->nn;
    double wpos = (double)ws->nn / s;
    double wneg = (double)ws->np / s;
    double edgel = (wpos * ws->bce_p + wneg * ws->bce_n) / (double)NPIX;
    out[0] = (float)(segl + 0.3 * edgel + 0.1 * attl);
  }
}

// ---------------------------------------------------------------- launch
extern "C" void kernel_launch(void* const* d_in, const int* in_sizes, int n_in,
                              void* d_out, int out_size, void* d_ws, size_t ws_size,
                              hipStream_t stream) {
  const float* segin   = (const float*)d_in[0];
  const float* edgein  = (const float*)d_in[1];
  const int*   segmask = (const int*)d_in[2];
  const int*   edgemask= (const int*)d_in[3];
  Ws* ws = (Ws*)d_ws;
  float* out = (float*)d_out;

  hipLaunchKernelGGL(k_init,  dim3(1),             dim3(256), 0, stream, ws);
  hipLaunchKernelGGL(k_fused, dim3(HW / TILE, NB), dim3(TPB), 0, stream, segin, edgein, segmask, edgemask, ws);
  hipLaunchKernelGGL(k_final, dim3(1),             dim3(1),   0, stream, ws, out);
}

// Round 6
// 301.622 us; speedup vs baseline: 1.1728x; 1.1728x over previous
//
#include <hip/hip_runtime.h>
#include <math.h>

#define CNUM 19
#define NB 4
#define HW 589824            // 768*768
#define NPIX 2359296         // NB*HW

// k_fused: 256 threads x 8 px = 2048 px/block -> grid (288, 4) = 4608 waves.
// Two independent float4 pixel-groups per thread: px t*4 and px 1024+t*4,
// so every global load instruction is a fully wave-contiguous 1KB burst and
// per-channel there are TWO independent loads (deeper MLP without longer
// dependent chains).
#define TPB 256
#define PXT 8
#define TILE (TPB * PXT)     // 2048; HW % TILE == 0
#define G1 1024              // offset of second pixel group within tile

// ---------------------------------------------------------------- workspace
struct ImgAcc2 {
  double sS[CNUM];          // sum of -log p over valid px of class c
  double sA[CNUM];          // same, att-masked (edge > 0.8)
  unsigned int cS[CNUM];    // count (== histogram bin)
  unsigned int cA[CNUM];    // att count (== att histogram bin)
  unsigned int pad[2];
};

struct Ws {
  ImgAcc2 img[NB];
  double bce_p, bce_n;      // sum of bce over pos / neg px (batch-global)
  unsigned int np, nn;      // pos / neg counts (batch-global)
};

// ---------------------------------------------------------------- init
__global__ void k_init(Ws* ws) {
  unsigned int* p = (unsigned int*)ws;
  const int nw = (int)(sizeof(Ws) / 4);
  for (int i = threadIdx.x; i < nw; i += blockDim.x) p[i] = 0u;
}

// ---------------------------------------------------------------- fused main
__global__ __launch_bounds__(TPB) void k_fused(const float* __restrict__ segin,
                                               const float* __restrict__ edgein,
                                               const int* __restrict__ segmask,
                                               const int* __restrict__ edgemask,
                                               Ws* __restrict__ wsw) {
  const int n = blockIdx.y;
  const int t = threadIdx.x;
  const int tile0 = blockIdx.x * TILE;

  // Per-wave accumulation rows: 4x less same-address contention than r5's
  // single shared row (which showed 308K bank-conflict cycles). +1 pad col.
  __shared__ float lsS[4][CNUM + 1], lsA[4][CNUM + 1];
  __shared__ unsigned int lcS[4][CNUM + 1], lcA[4][CNUM + 1];
  __shared__ float sbp, sbn;
  __shared__ unsigned int snp, snn;

  if (t < 4 * (CNUM + 1)) {
    ((float*)lsS)[t] = 0.f; ((float*)lsA)[t] = 0.f;
    ((unsigned int*)lcS)[t] = 0u; ((unsigned int*)lcA)[t] = 0u;
  }
  if (t == 128) { sbp = 0.f; sbn = 0.f; snp = 0u; snn = 0u; }
  __syncthreads();

  const int px0 = n * HW + tile0 + t * 4;        // group 0
  const int px1 = px0 + G1;                      // group 1

  // Only segmask is needed across the channel loop.
  int4 tm0 = *reinterpret_cast<const int4*>(segmask + px0);
  int4 tm1 = *reinterpret_cast<const int4*>(segmask + px1);
  int tcv[PXT];
  unsigned int inbits = 0u;    // bit j: 0 <= target < CNUM
  {
    int ta[PXT] = {tm0.x, tm0.y, tm0.z, tm0.w, tm1.x, tm1.y, tm1.z, tm1.w};
    #pragma unroll
    for (int j = 0; j < PXT; ++j) {
      tcv[j] = min(max(ta[j], 0), CNUM - 1);
      inbits |= (((unsigned)ta[j]) < (unsigned)CNUM) ? (1u << j) : 0u;
    }
  }

  float sacc[PXT], xt[PXT];
  #pragma unroll
  for (int j = 0; j < PXT; ++j) { sacc[j] = 0.f; xt[j] = 0.f; }

  const float* cb = segin + (size_t)n * CNUM * HW + tile0 + t * 4;
  #pragma unroll
  for (int c = 0; c < CNUM; ++c) {
    const float* p = cb + (size_t)c * HW;
    float4 v0 = *reinterpret_cast<const float4*>(p);
    float4 v1 = *reinterpret_cast<const float4*>(p + G1);
    float va[PXT] = {v0.x, v0.y, v0.z, v0.w, v1.x, v1.y, v1.z, v1.w};
    #pragma unroll
    for (int j = 0; j < PXT; ++j) {
      sacc[j] += __expf(va[j]);
      xt[j] = (tcv[j] == c) ? va[j] : xt[j];
    }
  }

  // Epilogue: edge data (small inputs), per-wave-row LDS accumulation.
  float4 e0 = *reinterpret_cast<const float4*>(edgein + px0);
  float4 e1 = *reinterpret_cast<const float4*>(edgein + px1);
  int4   m0 = *reinterpret_cast<const int4*>(edgemask + px0);
  int4   m1 = *reinterpret_cast<const int4*>(edgemask + px1);

  const int wv = t >> 6;
  float bpos = 0.f, bneg = 0.f;
  int cntp = 0, cntn = 0;
  {
    float ea[PXT] = {e0.x, e0.y, e0.z, e0.w, e1.x, e1.y, e1.z, e1.w};
    int   ma[PXT] = {m0.x, m0.y, m0.z, m0.w, m1.x, m1.y, m1.z, m1.w};
    #pragma unroll
    for (int j = 0; j < PXT; ++j) {
      float nlp = __logf(sacc[j]) - xt[j];     // -log p
      if ((inbits >> j) & 1u) {
        atomicAdd(&lsS[wv][tcv[j]], nlp);
        atomicAdd(&lcS[wv][tcv[j]], 1u);
        if (ea[j] > 0.8f) {
          atomicAdd(&lsA[wv][tcv[j]], nlp);
          atomicAdd(&lcA[wv][tcv[j]], 1u);
        }
      }
      float e = ea[j];
      int m = ma[j];
      float bce = fmaxf(e, 0.f) - e * (float)m + log1pf(__expf(-fabsf(e)));
      if (m == 1) { bpos += bce; ++cntp; }
      else if (m == 0) { bneg += bce; ++cntn; }
    }
  }

  // wave-reduce the bce partials, then one LDS atomic per wave
  #pragma unroll
  for (int off = 32; off > 0; off >>= 1) {
    bpos += __shfl_down(bpos, off);
    bneg += __shfl_down(bneg, off);
    cntp += __shfl_down(cntp, off);
    cntn += __shfl_down(cntn, off);
  }
  if ((t & 63) == 0) {
    atomicAdd(&sbp, bpos);
    atomicAdd(&sbn, bneg);
    atomicAdd(&snp, (unsigned int)cntp);
    atomicAdd(&snn, (unsigned int)cntn);
  }
  __syncthreads();

  // flush: sum the 4 wave rows, one global atomic per accumulator
  if (t < CNUM) {
    float v = lsS[0][t] + lsS[1][t] + lsS[2][t] + lsS[3][t];
    atomicAdd(&wsw->img[n].sS[t], (double)v);
  } else if (t >= 32 && t < 32 + CNUM) {
    int c = t - 32;
    float v = lsA[0][c] + lsA[1][c] + lsA[2][c] + lsA[3][c];
    atomicAdd(&wsw->img[n].sA[c], (double)v);
  } else if (t >= 64 && t < 64 + CNUM) {
    int c = t - 64;
    unsigned int v = lcS[0][c] + lcS[1][c] + lcS[2][c] + lcS[3][c];
    if (v) atomicAdd(&wsw->img[n].cS[c], v);
  } else if (t >= 96 && t < 96 + CNUM) {
    int c = t - 96;
    unsigned int v = lcA[0][c] + lcA[1][c] + lcA[2][c] + lcA[3][c];
    if (v) atomicAdd(&wsw->img[n].cA[c], v);
  } else if (t == 128) {
    atomicAdd(&wsw->bce_p, (double)sbp);
  } else if (t == 129) {
    atomicAdd(&wsw->bce_n, (double)sbn);
  } else if (t == 130) {
    atomicAdd(&wsw->np, snp);
  } else if (t == 131) {
    atomicAdd(&wsw->nn, snn);
  }
}

// ---------------------------------------------------------------- finalize
__global__ void k_final(const Ws* __restrict__ ws, float* __restrict__ out) {
  if (threadIdx.x == 0 && blockIdx.x == 0) {
    double segl = 0.0, attl = 0.0;
    for (int i = 0; i < NB; ++i) {
      const ImgAcc2* a = &ws->img[i];
      double totS = 0.0, totA = 0.0;
      for (int c = 0; c < CNUM; ++c) { totS += (double)a->cS[c]; totA += (double)a->cA[c]; }
      double numS = 0.0, denS = 0.0, numA = 0.0, denA = 0.0;
      for (int c = 0; c < CNUM; ++c) {
        double bS = (double)a->cS[c];
        double wS = (bS != 0.0 ? (1.0 - bS / totS) : 0.0) + 1.0;
        numS += wS * a->sS[c];
        denS += wS * bS;
        double bA = (double)a->cA[c];
        double wA = (bA != 0.0 ? (1.0 - bA / totA) : 0.0) + 1.0;
        numA += wA * a->sA[c];
        denA += wA * bA;
      }
      segl += numS / denS;
      attl += numA / denA;
    }
    double s = (double)ws->np + (double)ws->nn;
    double wpos = (double)ws->nn / s;
    double wneg = (double)ws->np / s;
    double edgel = (wpos * ws->bce_p + wneg * ws->bce_n) / (double)NPIX;
    out[0] = (float)(segl + 0.3 * edgel + 0.1 * attl);
  }
}

// ---------------------------------------------------------------- launch
extern "C" void kernel_launch(void* const* d_in, const int* in_sizes, int n_in,
                              void* d_out, int out_size, void* d_ws, size_t ws_size,
                              hipStream_t stream) {
  const float* segin   = (const float*)d_in[0];
  const float* edgein  = (const float*)d_in[1];
  const int*   segmask = (const int*)d_in[2];
  const int*   edgemask= (const int*)d_in[3];
  Ws* ws = (Ws*)d_ws;
  float* out = (float*)d_out;

  hipLaunchKernelGGL(k_init,  dim3(1),             dim3(256), 0, stream, ws);
  hipLaunchKernelGGL(k_fused, dim3(HW / TILE, NB), dim3(TPB), 0, stream, segin, edgein, segmask, edgemask, ws);
  hipLaunchKernelGGL(k_final, dim3(1),             dim3(1),   0, stream, ws, out);
}